// Round 1
// baseline (2466.223 us; speedup 1.0000x reference)
//
#include <hip/hip_runtime.h>
#include <hip/hip_cooperative_groups.h>

// Problem constants: B=32, TX=TY=64, D=H=512, 4H=2048, V=32000.
typedef unsigned short ushort_t;
typedef __attribute__((ext_vector_type(8))) short short8;   // 8 bf16 = 4 VGPRs
typedef __attribute__((ext_vector_type(4))) float f32x4;    // MFMA 16x16 accumulator

__device__ __forceinline__ ushort_t f2bf(float x) {
  union { float f; unsigned int u; } v; v.f = x;
  unsigned int r = v.u + 0x7fffu + ((v.u >> 16) & 1u);  // RNE
  return (ushort_t)(r >> 16);
}
__device__ __forceinline__ float bf2f(ushort_t h) {
  union { unsigned int u; float f; } v; v.u = ((unsigned int)h) << 16; return v.f;
}
__device__ __forceinline__ void splitbf(float x, ushort_t& hi, ushort_t& lo) {
  hi = f2bf(x);
  lo = f2bf(x - bf2f(hi));
}
__device__ __forceinline__ float sigm(float x) { return 1.f / (1.f + expf(-x)); }
__device__ __forceinline__ f32x4 mfma16(short8 a, short8 b, f32x4 c) {
  return __builtin_amdgcn_mfma_f32_16x16x32_bf16(a, b, c, 0, 0, 0);
}

// ---------------------------------------------------------------------------
// Transpose + split: src fp32 [Krows][ld] (row offset k0) -> hi/lo bf16 [N][512]
// grid: (N/64, 512/64), block 256.
__global__ void __launch_bounds__(256) transpose_split(
    const float* __restrict__ src, int ld, int k0,
    ushort_t* __restrict__ hi, ushort_t* __restrict__ lo) {
  __shared__ float tile[64][65];
  const int n0 = blockIdx.x * 64, kb = blockIdx.y * 64;
  #pragma unroll
  for (int i = 0; i < 16; ++i) {
    int idx = i * 256 + threadIdx.x;
    int kk = idx >> 6, nn = idx & 63;
    tile[kk][nn] = src[(size_t)(k0 + kb + kk) * ld + n0 + nn];
  }
  __syncthreads();
  #pragma unroll
  for (int i = 0; i < 16; ++i) {
    int idx = i * 256 + threadIdx.x;
    int nn = idx >> 6, kk = idx & 63;
    float x = tile[kk][nn];
    ushort_t h, l; splitbf(x, h, l);
    size_t o = (size_t)(n0 + nn) * 512 + kb + kk;
    hi[o] = h; lo[o] = l;
  }
}

// ---------------------------------------------------------------------------
// Embedding gather + split: row m = t*32+b of A gets E[ids[b*T+t]].
// grid: 2048 blocks, 128 threads (each thread one float4 of the 512-wide row).
__global__ void __launch_bounds__(128) embed_split(
    const int* __restrict__ ids, const float* __restrict__ E,
    ushort_t* __restrict__ Ahi, ushort_t* __restrict__ Alo, int T) {
  const int m = blockIdx.x;
  const int b = m & 31, t = m >> 5;
  const int id = ids[b * T + t];
  float4 v = ((const float4*)(E + (size_t)id * 512))[threadIdx.x];
  ushort_t h0, l0, h1, l1, h2, l2, h3, l3;
  splitbf(v.x, h0, l0); splitbf(v.y, h1, l1);
  splitbf(v.z, h2, l2); splitbf(v.w, h3, l3);
  ushort4 hv = make_ushort4(h0, h1, h2, h3);
  ushort4 lv = make_ushort4(l0, l1, l2, l3);
  ((ushort4*)(Ahi + (size_t)m * 512))[threadIdx.x] = hv;
  ((ushort4*)(Alo + (size_t)m * 512))[threadIdx.x] = lv;
}

// ---------------------------------------------------------------------------
// Split-bf16 3-pass GEMM: C[M][N] = (Ahi+Alo)[M][512] * (Bhi+Blo)^T[N][512] (+bias)
// Block tile 128x128, 4 waves of 64x64 (4x4 of 16x16x32 MFMA). K = 512 fixed.
// LDS tiles 128x64 per array (64 KB total), 16B-chunk XOR swizzle for frag reads.
__global__ void __launch_bounds__(256, 2) gemm_split(
    const ushort_t* __restrict__ Ahi, const ushort_t* __restrict__ Alo,
    const ushort_t* __restrict__ Bhi, const ushort_t* __restrict__ Blo,
    const float* __restrict__ bias, float* __restrict__ C, int M, int N) {
  __shared__ __align__(16) ushort_t lAh[128 * 64];
  __shared__ __align__(16) ushort_t lAl[128 * 64];
  __shared__ __align__(16) ushort_t lBh[128 * 64];
  __shared__ __align__(16) ushort_t lBl[128 * 64];
  const int tid = threadIdx.x;
  const int lane = tid & 63, w = tid >> 6;
  const int wm = (w >> 1) * 64, wn = (w & 1) * 64;
  const int lm = lane & 15, lq = lane >> 4;
  const int m0 = blockIdx.y * 128, n0 = blockIdx.x * 128;

  f32x4 acc[4][4];
  #pragma unroll
  for (int i = 0; i < 4; ++i)
    #pragma unroll
    for (int j = 0; j < 4; ++j)
      acc[i][j] = (f32x4){0.f, 0.f, 0.f, 0.f};

  for (int kc = 0; kc < 8; ++kc) {
    if (kc) __syncthreads();  // WAR: previous chunk's frag reads done
    #pragma unroll
    for (int i = 0; i < 4; ++i) {
      int cid = i * 256 + tid;            // 0..1023 16B-chunks per array
      int r = cid >> 3, c = cid & 7;
      int cs = c ^ (r & 7);
      size_t goffA = (size_t)(m0 + r) * 512 + kc * 64 + c * 8;
      size_t goffB = (size_t)(n0 + r) * 512 + kc * 64 + c * 8;
      *(uint4*)&lAh[r * 64 + cs * 8] = *(const uint4*)(Ahi + goffA);
      *(uint4*)&lAl[r * 64 + cs * 8] = *(const uint4*)(Alo + goffA);
      *(uint4*)&lBh[r * 64 + cs * 8] = *(const uint4*)(Bhi + goffB);
      *(uint4*)&lBl[r * 64 + cs * 8] = *(const uint4*)(Blo + goffB);
    }
    __syncthreads();
    #pragma unroll
    for (int ks = 0; ks < 2; ++ks) {
      short8 ah[4], al[4], bh[4], bl[4];
      #pragma unroll
      for (int t = 0; t < 4; ++t) {
        int ra = wm + t * 16 + lm;
        int ca = (ks * 4 + lq) ^ (ra & 7);
        ah[t] = *(const short8*)&lAh[ra * 64 + ca * 8];
        al[t] = *(const short8*)&lAl[ra * 64 + ca * 8];
        int rb = wn + t * 16 + lm;
        int cb = (ks * 4 + lq) ^ (rb & 7);
        bh[t] = *(const short8*)&lBh[rb * 64 + cb * 8];
        bl[t] = *(const short8*)&lBl[rb * 64 + cb * 8];
      }
      #pragma unroll
      for (int mt = 0; mt < 4; ++mt)
        #pragma unroll
        for (int nt = 0; nt < 4; ++nt) {
          acc[mt][nt] = mfma16(ah[mt], bh[nt], acc[mt][nt]);
          acc[mt][nt] = mfma16(ah[mt], bl[nt], acc[mt][nt]);
          acc[mt][nt] = mfma16(al[mt], bh[nt], acc[mt][nt]);
        }
    }
  }
  // epilogue: C/D layout col=lane&15, row=(lane>>4)*4+reg
  #pragma unroll
  for (int nt = 0; nt < 4; ++nt) {
    int col = n0 + wn + nt * 16 + lm;
    float bv = bias ? bias[col] : 0.f;
    #pragma unroll
    for (int mt = 0; mt < 4; ++mt) {
      int rbase = m0 + wm + mt * 16 + lq * 4;
      #pragma unroll
      for (int r = 0; r < 4; ++r)
        C[(size_t)(rbase + r) * N + col] = acc[mt][nt][r] + bv;
    }
  }
}

// ---------------------------------------------------------------------------
// Full enc+dec recurrence: 64 blocks x 256 thr, cooperative, 1 grid.sync/step.
// Block = (bm in {0,1}: 16-batch tile) x (jg in [0,32): 16 H-cols). Wave = gate.
// Wh fragments live in registers (16 ks x hi/lo = 128 VGPRs). h ping-pongs in
// global as split bf16; c/h carried exactly in fp32 in LDS per-block slices.
__global__ void __launch_bounds__(256, 1) lstm_recurrence(
    const ushort_t* __restrict__ eWh_hi, const ushort_t* __restrict__ eWh_lo,
    const ushort_t* __restrict__ dWh_hi, const ushort_t* __restrict__ dWh_lo,
    const float* __restrict__ xz_enc, const float* __restrict__ xz_dec,
    const int* __restrict__ len_enc, const int* __restrict__ len_dec,
    ushort_t* __restrict__ h_hi0, ushort_t* __restrict__ h_lo0,
    ushort_t* __restrict__ h_hi1, ushort_t* __restrict__ h_lo1,
    ushort_t* __restrict__ hs_hi, ushort_t* __restrict__ hs_lo) {
  cooperative_groups::grid_group grid = cooperative_groups::this_grid();
  const int tid = threadIdx.x;
  const int lane = tid & 63, g = tid >> 6;       // g = gate (i,j,f,o)
  const int lm = lane & 15, lq = lane >> 4;
  const int bm = blockIdx.x & 1, jg = blockIdx.x >> 1;

  __shared__ float z_x[4][16][17];
  __shared__ float c_st[16][17], h_st[16][17];

  const int bl = tid >> 4, nn = tid & 15;        // gate-phase mapping
  const int bglob = bm * 16 + bl;
  const int hcol = jg * 16 + nn;

  c_st[bl][nn] = 0.f; h_st[bl][nn] = 0.f;
  h_hi0[bglob * 512 + hcol] = 0; h_lo0[bglob * 512 + hcol] = 0;
  const int lenE = len_enc[bglob], lenD = len_dec[bglob];

  // Preload encoder Wh fragments into registers.
  short8 fbh[16], fbl[16];
  const size_t browoff = (size_t)(g * 512 + jg * 16 + lm) * 512 + lq * 8;
  #pragma unroll
  for (int ks = 0; ks < 16; ++ks) {
    fbh[ks] = *(const short8*)(eWh_hi + browoff + ks * 32);
    fbl[ks] = *(const short8*)(eWh_lo + browoff + ks * 32);
  }
  grid.sync();

  const size_t arow = (size_t)(bm * 16 + lm) * 512 + lq * 8;

  #pragma unroll 1
  for (int s = 0; s < 128; ++s) {
    if (s == 64) {  // switch to decoder weights (uniform branch)
      #pragma unroll
      for (int ks = 0; ks < 16; ++ks) {
        fbh[ks] = *(const short8*)(dWh_hi + browoff + ks * 32);
        fbl[ks] = *(const short8*)(dWh_lo + browoff + ks * 32);
      }
    }
    const ushort_t* hh = (s & 1) ? h_hi1 : h_hi0;
    const ushort_t* hl = (s & 1) ? h_lo1 : h_lo0;
    ushort_t* ohh = (s & 1) ? h_hi0 : h_hi1;
    ushort_t* ohl = (s & 1) ? h_lo0 : h_lo1;

    f32x4 acc = (f32x4){0.f, 0.f, 0.f, 0.f};
    #pragma unroll
    for (int ks = 0; ks < 16; ++ks) {
      short8 ah = *(const short8*)(hh + arow + ks * 32);
      short8 al = *(const short8*)(hl + arow + ks * 32);
      acc = mfma16(ah, fbh[ks], acc);
      acc = mfma16(ah, fbl[ks], acc);
      acc = mfma16(al, fbh[ks], acc);
    }
    #pragma unroll
    for (int r = 0; r < 4; ++r) z_x[g][lq * 4 + r][lm] = acc[r];
    __syncthreads();

    {  // gate phase: thread (bl, nn) owns one (b, H-col) cell
      const bool isdec = s >= 64;
      const int t = isdec ? s - 64 : s;
      const float* xz = isdec ? xz_dec : xz_enc;
      const int len = isdec ? lenD : lenE;
      const size_t base = ((size_t)t * 32 + bglob) * 2048 + jg * 16 + nn;
      float zi = z_x[0][bl][nn] + xz[base];
      float zj = z_x[1][bl][nn] + xz[base + 512];
      float zf = z_x[2][bl][nn] + xz[base + 1024];
      float zo = z_x[3][bl][nn] + xz[base + 1536];
      float co = c_st[bl][nn], ho = h_st[bl][nn];
      float cn = co * sigm(zf + 1.0f) + sigm(zi) * tanhf(zj);  // forget bias 1.0
      float hn = tanhf(cn) * sigm(zo);
      bool msk = t < len;
      float ck = msk ? cn : co;
      float hk = msk ? hn : ho;
      c_st[bl][nn] = ck; h_st[bl][nn] = hk;
      ushort_t hi, lo;
      splitbf(hk, hi, lo);
      ohh[bglob * 512 + hcol] = hi;
      ohl[bglob * 512 + hcol] = lo;
      if (isdec) {  // emitted output: zeroed past length; row = b*64 + t
        float hv = msk ? hn : 0.f;
        splitbf(hv, hi, lo);
        hs_hi[((size_t)bglob * 64 + t) * 512 + hcol] = hi;
        hs_lo[((size_t)bglob * 64 + t) * 512 + hcol] = lo;
      }
    }
    grid.sync();
  }
}

// ---------------------------------------------------------------------------
extern "C" void kernel_launch(void* const* d_in, const int* in_sizes, int n_in,
                              void* d_out, int out_size, void* d_ws, size_t ws_size,
                              hipStream_t stream) {
  (void)in_sizes; (void)n_in; (void)out_size; (void)ws_size;
  const int*   enc_ids = (const int*)d_in[0];
  const int*   dec_ids = (const int*)d_in[1];
  const int*   len_enc = (const int*)d_in[2];
  const int*   len_dec = (const int*)d_in[3];
  const float* E       = (const float*)d_in[4];
  const float* enc_W   = (const float*)d_in[5];
  const float* enc_b   = (const float*)d_in[6];
  const float* dec_W   = (const float*)d_in[7];
  const float* dec_b   = (const float*)d_in[8];
  const float* proj_W  = (const float*)d_in[9];

  char* w = (char*)d_ws;
  auto carve = [&](size_t bytes) -> char* {
    char* p = w; w += (bytes + 255) & ~(size_t)255; return p;
  };
  const size_t WSZ = 2048 * 512 * 2;  // [2048][512] bf16
  ushort_t* eWx_hi = (ushort_t*)carve(WSZ); ushort_t* eWx_lo = (ushort_t*)carve(WSZ);
  ushort_t* eWh_hi = (ushort_t*)carve(WSZ); ushort_t* eWh_lo = (ushort_t*)carve(WSZ);
  ushort_t* dWx_hi = (ushort_t*)carve(WSZ); ushort_t* dWx_lo = (ushort_t*)carve(WSZ);
  ushort_t* dWh_hi = (ushort_t*)carve(WSZ); ushort_t* dWh_lo = (ushort_t*)carve(WSZ);
  ushort_t* pW_hi  = (ushort_t*)carve((size_t)32000 * 512 * 2);
  ushort_t* pW_lo  = (ushort_t*)carve((size_t)32000 * 512 * 2);
  ushort_t* Ae_hi  = (ushort_t*)carve(WSZ); ushort_t* Ae_lo = (ushort_t*)carve(WSZ);
  ushort_t* Ad_hi  = (ushort_t*)carve(WSZ); ushort_t* Ad_lo = (ushort_t*)carve(WSZ);
  float* xz_enc = (float*)carve((size_t)64 * 32 * 2048 * 4);
  float* xz_dec = (float*)carve((size_t)64 * 32 * 2048 * 4);
  ushort_t* hs_hi = (ushort_t*)carve(WSZ); ushort_t* hs_lo = (ushort_t*)carve(WSZ);
  ushort_t* h_hi0 = (ushort_t*)carve(32 * 512 * 2);
  ushort_t* h_lo0 = (ushort_t*)carve(32 * 512 * 2);
  ushort_t* h_hi1 = (ushort_t*)carve(32 * 512 * 2);
  ushort_t* h_lo1 = (ushort_t*)carve(32 * 512 * 2);

  dim3 blk(256);
  // Weight transpose+split (B^T layout [n][k] for contiguous MFMA B-fragments)
  transpose_split<<<dim3(32, 8),  blk, 0, stream>>>(enc_W, 2048, 0,   eWx_hi, eWx_lo);
  transpose_split<<<dim3(32, 8),  blk, 0, stream>>>(enc_W, 2048, 512, eWh_hi, eWh_lo);
  transpose_split<<<dim3(32, 8),  blk, 0, stream>>>(dec_W, 2048, 0,   dWx_hi, dWx_lo);
  transpose_split<<<dim3(32, 8),  blk, 0, stream>>>(dec_W, 2048, 512, dWh_hi, dWh_lo);
  transpose_split<<<dim3(500, 8), blk, 0, stream>>>(proj_W, 32000, 0, pW_hi, pW_lo);

  // Embedding gather+split (rows m = t*32+b)
  embed_split<<<2048, 128, 0, stream>>>(enc_ids, E, Ae_hi, Ae_lo, 64);
  embed_split<<<2048, 128, 0, stream>>>(dec_ids, E, Ad_hi, Ad_lo, 64);

  // Input-side gate pre-activations: xz[t][b][4H] = X @ W_x + b
  gemm_split<<<dim3(16, 16), blk, 0, stream>>>(Ae_hi, Ae_lo, eWx_hi, eWx_lo,
                                               enc_b, xz_enc, 2048, 2048);
  gemm_split<<<dim3(16, 16), blk, 0, stream>>>(Ad_hi, Ad_lo, dWx_hi, dWx_lo,
                                               dec_b, xz_dec, 2048, 2048);

  // Recurrence (cooperative: grid-wide sync per step)
  void* args[] = { &eWh_hi, &eWh_lo, &dWh_hi, &dWh_lo,
                   (void*)&xz_enc, (void*)&xz_dec,
                   (void*)&len_enc, (void*)&len_dec,
                   &h_hi0, &h_lo0, &h_hi1, &h_lo1, &hs_hi, &hs_lo };
  hipLaunchCooperativeKernel((void*)lstm_recurrence, dim3(64), dim3(256),
                             args, 0, stream);

  // Vocab projection: out[b][t][v], row m = b*64+t matches hs layout.
  const float* nobias = nullptr;
  gemm_split<<<dim3(250, 16), blk, 0, stream>>>(hs_hi, hs_lo, pW_hi, pW_lo,
                                                nobias, (float*)d_out, 2048, 32000);
}

// Round 2
// 1830.980 us; speedup vs baseline: 1.3469x; 1.3469x over previous
//
#include <hip/hip_runtime.h>

// Problem constants: B=32, TX=TY=64, D=H=512, 4H=2048, V=32000.
typedef unsigned short ushort_t;
typedef __attribute__((ext_vector_type(8))) short short8;   // 8 bf16 = 4 VGPRs
typedef __attribute__((ext_vector_type(4))) float f32x4;    // MFMA 16x16 accumulator

__device__ __forceinline__ ushort_t f2bf(float x) {
  union { float f; unsigned int u; } v; v.f = x;
  unsigned int r = v.u + 0x7fffu + ((v.u >> 16) & 1u);  // RNE
  return (ushort_t)(r >> 16);
}
__device__ __forceinline__ float bf2f(ushort_t h) {
  union { unsigned int u; float f; } v; v.u = ((unsigned int)h) << 16; return v.f;
}
__device__ __forceinline__ void splitbf(float x, ushort_t& hi, ushort_t& lo) {
  hi = f2bf(x);
  lo = f2bf(x - bf2f(hi));
}
__device__ __forceinline__ float sigm(float x) { return 1.f / (1.f + expf(-x)); }
__device__ __forceinline__ f32x4 mfma16(short8 a, short8 b, f32x4 c) {
  return __builtin_amdgcn_mfma_f32_16x16x32_bf16(a, b, c, 0, 0, 0);
}

// Flat all-to-all grid barrier over NB blocks. flags[i*32] = arrival counter of
// block i (128B padded slots). Poisoned ws reads as negative int -> no init
// needed (counters are monotone within a launch; ws re-poisoned every launch).
#define BAR_NB 64
__device__ __forceinline__ void gridbar(int* __restrict__ flags, int bid,
                                        int tid, int bar) {
  __syncthreads();  // all 256 threads' work (incl. global stores) issued+drained
  if (tid == 0)
    __hip_atomic_store(&flags[bid * 32], bar, __ATOMIC_RELEASE,
                       __HIP_MEMORY_SCOPE_AGENT);
  if (tid < BAR_NB) {
    while (__hip_atomic_load(&flags[tid * 32], __ATOMIC_RELAXED,
                             __HIP_MEMORY_SCOPE_AGENT) < bar) {}
  }
  __syncthreads();
  __builtin_amdgcn_fence(__ATOMIC_ACQUIRE, "agent");  // invalidate L1/L2 lines
}

// ---------------------------------------------------------------------------
// Transpose + split: src fp32 [Krows][ld] (row offset k0) -> hi/lo bf16 [N][512]
// grid: (N/64, 512/64), block 256.
__global__ void __launch_bounds__(256) transpose_split(
    const float* __restrict__ src, int ld, int k0,
    ushort_t* __restrict__ hi, ushort_t* __restrict__ lo) {
  __shared__ float tile[64][65];
  const int n0 = blockIdx.x * 64, kb = blockIdx.y * 64;
  #pragma unroll
  for (int i = 0; i < 16; ++i) {
    int idx = i * 256 + threadIdx.x;
    int kk = idx >> 6, nn = idx & 63;
    tile[kk][nn] = src[(size_t)(k0 + kb + kk) * ld + n0 + nn];
  }
  __syncthreads();
  #pragma unroll
  for (int i = 0; i < 16; ++i) {
    int idx = i * 256 + threadIdx.x;
    int nn = idx >> 6, kk = idx & 63;
    float x = tile[kk][nn];
    ushort_t h, l; splitbf(x, h, l);
    size_t o = (size_t)(n0 + nn) * 512 + kb + kk;
    hi[o] = h; lo[o] = l;
  }
}

// ---------------------------------------------------------------------------
// Embedding gather + split: row m = t*32+b of A gets E[ids[b*T+t]].
__global__ void __launch_bounds__(128) embed_split(
    const int* __restrict__ ids, const float* __restrict__ E,
    ushort_t* __restrict__ Ahi, ushort_t* __restrict__ Alo, int T) {
  const int m = blockIdx.x;
  const int b = m & 31, t = m >> 5;
  const int id = ids[b * T + t];
  float4 v = ((const float4*)(E + (size_t)id * 512))[threadIdx.x];
  ushort_t h0, l0, h1, l1, h2, l2, h3, l3;
  splitbf(v.x, h0, l0); splitbf(v.y, h1, l1);
  splitbf(v.z, h2, l2); splitbf(v.w, h3, l3);
  ushort4 hv = make_ushort4(h0, h1, h2, h3);
  ushort4 lv = make_ushort4(l0, l1, l2, l3);
  ((ushort4*)(Ahi + (size_t)m * 512))[threadIdx.x] = hv;
  ((ushort4*)(Alo + (size_t)m * 512))[threadIdx.x] = lv;
}

// ---------------------------------------------------------------------------
// Split-bf16 3-pass GEMM: C[M][N] = (Ahi+Alo)[M][512] * (Bhi+Blo)^T[N][512] (+bias)
// Block tile 128x128, 4 waves of 64x64 (4x4 of 16x16x32 MFMA). K = 512 fixed.
__global__ void __launch_bounds__(256, 2) gemm_split(
    const ushort_t* __restrict__ Ahi, const ushort_t* __restrict__ Alo,
    const ushort_t* __restrict__ Bhi, const ushort_t* __restrict__ Blo,
    const float* __restrict__ bias, float* __restrict__ C, int M, int N) {
  __shared__ __align__(16) ushort_t lAh[128 * 64];
  __shared__ __align__(16) ushort_t lAl[128 * 64];
  __shared__ __align__(16) ushort_t lBh[128 * 64];
  __shared__ __align__(16) ushort_t lBl[128 * 64];
  const int tid = threadIdx.x;
  const int lane = tid & 63, w = tid >> 6;
  const int wm = (w >> 1) * 64, wn = (w & 1) * 64;
  const int lm = lane & 15, lq = lane >> 4;
  const int m0 = blockIdx.y * 128, n0 = blockIdx.x * 128;

  f32x4 acc[4][4];
  #pragma unroll
  for (int i = 0; i < 4; ++i)
    #pragma unroll
    for (int j = 0; j < 4; ++j)
      acc[i][j] = (f32x4){0.f, 0.f, 0.f, 0.f};

  for (int kc = 0; kc < 8; ++kc) {
    if (kc) __syncthreads();  // WAR: previous chunk's frag reads done
    #pragma unroll
    for (int i = 0; i < 4; ++i) {
      int cid = i * 256 + tid;            // 0..1023 16B-chunks per array
      int r = cid >> 3, c = cid & 7;
      int cs = c ^ (r & 7);
      size_t goffA = (size_t)(m0 + r) * 512 + kc * 64 + c * 8;
      size_t goffB = (size_t)(n0 + r) * 512 + kc * 64 + c * 8;
      *(uint4*)&lAh[r * 64 + cs * 8] = *(const uint4*)(Ahi + goffA);
      *(uint4*)&lAl[r * 64 + cs * 8] = *(const uint4*)(Alo + goffA);
      *(uint4*)&lBh[r * 64 + cs * 8] = *(const uint4*)(Bhi + goffB);
      *(uint4*)&lBl[r * 64 + cs * 8] = *(const uint4*)(Blo + goffB);
    }
    __syncthreads();
    #pragma unroll
    for (int ks = 0; ks < 2; ++ks) {
      short8 ah[4], al[4], bh[4], bl[4];
      #pragma unroll
      for (int t = 0; t < 4; ++t) {
        int ra = wm + t * 16 + lm;
        int ca = (ks * 4 + lq) ^ (ra & 7);
        ah[t] = *(const short8*)&lAh[ra * 64 + ca * 8];
        al[t] = *(const short8*)&lAl[ra * 64 + ca * 8];
        int rb = wn + t * 16 + lm;
        int cb = (ks * 4 + lq) ^ (rb & 7);
        bh[t] = *(const short8*)&lBh[rb * 64 + cb * 8];
        bl[t] = *(const short8*)&lBl[rb * 64 + cb * 8];
      }
      #pragma unroll
      for (int mt = 0; mt < 4; ++mt)
        #pragma unroll
        for (int nt = 0; nt < 4; ++nt) {
          acc[mt][nt] = mfma16(ah[mt], bh[nt], acc[mt][nt]);
          acc[mt][nt] = mfma16(ah[mt], bl[nt], acc[mt][nt]);
          acc[mt][nt] = mfma16(al[mt], bh[nt], acc[mt][nt]);
        }
    }
  }
  // epilogue: C/D layout col=lane&15, row=(lane>>4)*4+reg
  #pragma unroll
  for (int nt = 0; nt < 4; ++nt) {
    int col = n0 + wn + nt * 16 + lm;
    float bv = bias ? bias[col] : 0.f;
    #pragma unroll
    for (int mt = 0; mt < 4; ++mt) {
      int rbase = m0 + wm + mt * 16 + lq * 4;
      #pragma unroll
      for (int r = 0; r < 4; ++r)
        C[(size_t)(rbase + r) * N + col] = acc[mt][nt][r] + bv;
    }
  }
}

// ---------------------------------------------------------------------------
// Full enc+dec recurrence: 64 blocks x 256 thr, cooperative (for co-residency),
// 1 custom flags-barrier per step (grid.sync measured ~14 us/step - R1).
// Block = (bm in {0,1}: 16-batch tile) x (jg in [0,32): 16 H-cols). Wave = gate.
// Wh fragments live in registers; h ping-pongs in global as split bf16.
__global__ void __launch_bounds__(256, 1) lstm_recurrence(
    const ushort_t* __restrict__ eWh_hi, const ushort_t* __restrict__ eWh_lo,
    const ushort_t* __restrict__ dWh_hi, const ushort_t* __restrict__ dWh_lo,
    const float* __restrict__ xz_enc, const float* __restrict__ xz_dec,
    const int* __restrict__ len_enc, const int* __restrict__ len_dec,
    ushort_t* __restrict__ h_hi0, ushort_t* __restrict__ h_lo0,
    ushort_t* __restrict__ h_hi1, ushort_t* __restrict__ h_lo1,
    ushort_t* __restrict__ hs_hi, ushort_t* __restrict__ hs_lo,
    int* __restrict__ flags) {
  const int tid = threadIdx.x;
  const int lane = tid & 63, g = tid >> 6;       // g = gate (i,j,f,o)
  const int lm = lane & 15, lq = lane >> 4;
  const int bm = blockIdx.x & 1, jg = blockIdx.x >> 1;

  __shared__ float z_x[4][16][17];
  __shared__ float c_st[16][17], h_st[16][17];

  const int bl = tid >> 4, nn = tid & 15;        // gate-phase mapping
  const int bglob = bm * 16 + bl;
  const int hcol = jg * 16 + nn;

  c_st[bl][nn] = 0.f; h_st[bl][nn] = 0.f;
  h_hi0[bglob * 512 + hcol] = 0; h_lo0[bglob * 512 + hcol] = 0;
  const int lenE = len_enc[bglob], lenD = len_dec[bglob];

  // Preload encoder Wh fragments into registers.
  short8 fbh[16], fbl[16];
  const size_t browoff = (size_t)(g * 512 + jg * 16 + lm) * 512 + lq * 8;
  #pragma unroll
  for (int ks = 0; ks < 16; ++ks) {
    fbh[ks] = *(const short8*)(eWh_hi + browoff + ks * 32);
    fbl[ks] = *(const short8*)(eWh_lo + browoff + ks * 32);
  }
  gridbar(flags, blockIdx.x, tid, 1);   // h0 visible everywhere

  const size_t arow = (size_t)(bm * 16 + lm) * 512 + lq * 8;

  #pragma unroll 1
  for (int s = 0; s < 128; ++s) {
    if (s == 64) {  // switch to decoder weights (uniform branch)
      #pragma unroll
      for (int ks = 0; ks < 16; ++ks) {
        fbh[ks] = *(const short8*)(dWh_hi + browoff + ks * 32);
        fbl[ks] = *(const short8*)(dWh_lo + browoff + ks * 32);
      }
    }
    const ushort_t* hh = (s & 1) ? h_hi1 : h_hi0;
    const ushort_t* hl = (s & 1) ? h_lo1 : h_lo0;
    ushort_t* ohh = (s & 1) ? h_hi0 : h_hi1;
    ushort_t* ohl = (s & 1) ? h_lo0 : h_lo1;

    f32x4 acc = (f32x4){0.f, 0.f, 0.f, 0.f};
    #pragma unroll
    for (int ks = 0; ks < 16; ++ks) {
      short8 ah = *(const short8*)(hh + arow + ks * 32);
      short8 al = *(const short8*)(hl + arow + ks * 32);
      acc = mfma16(ah, fbh[ks], acc);
      acc = mfma16(ah, fbl[ks], acc);
      acc = mfma16(al, fbh[ks], acc);
    }
    #pragma unroll
    for (int r = 0; r < 4; ++r) z_x[g][lq * 4 + r][lm] = acc[r];
    __syncthreads();

    {  // gate phase: thread (bl, nn) owns one (b, H-col) cell
      const bool isdec = s >= 64;
      const int t = isdec ? s - 64 : s;
      const float* xz = isdec ? xz_dec : xz_enc;
      const int len = isdec ? lenD : lenE;
      const size_t base = ((size_t)t * 32 + bglob) * 2048 + jg * 16 + nn;
      float zi = z_x[0][bl][nn] + xz[base];
      float zj = z_x[1][bl][nn] + xz[base + 512];
      float zf = z_x[2][bl][nn] + xz[base + 1024];
      float zo = z_x[3][bl][nn] + xz[base + 1536];
      float co = c_st[bl][nn], ho = h_st[bl][nn];
      float cn = co * sigm(zf + 1.0f) + sigm(zi) * tanhf(zj);  // forget bias 1.0
      float hn = tanhf(cn) * sigm(zo);
      bool msk = t < len;
      float ck = msk ? cn : co;
      float hk = msk ? hn : ho;
      c_st[bl][nn] = ck; h_st[bl][nn] = hk;
      ushort_t hi, lo;
      splitbf(hk, hi, lo);
      ohh[bglob * 512 + hcol] = hi;
      ohl[bglob * 512 + hcol] = lo;
      if (isdec) {  // emitted output: zeroed past length; row = b*64 + t
        float hv = msk ? hn : 0.f;
        splitbf(hv, hi, lo);
        hs_hi[((size_t)bglob * 64 + t) * 512 + hcol] = hi;
        hs_lo[((size_t)bglob * 64 + t) * 512 + hcol] = lo;
      }
    }
    if (s != 127) gridbar(flags, blockIdx.x, tid, s + 2);
  }
}

// ---------------------------------------------------------------------------
extern "C" void kernel_launch(void* const* d_in, const int* in_sizes, int n_in,
                              void* d_out, int out_size, void* d_ws, size_t ws_size,
                              hipStream_t stream) {
  (void)in_sizes; (void)n_in; (void)out_size; (void)ws_size;
  const int*   enc_ids = (const int*)d_in[0];
  const int*   dec_ids = (const int*)d_in[1];
  const int*   len_enc = (const int*)d_in[2];
  const int*   len_dec = (const int*)d_in[3];
  const float* E       = (const float*)d_in[4];
  const float* enc_W   = (const float*)d_in[5];
  const float* enc_b   = (const float*)d_in[6];
  const float* dec_W   = (const float*)d_in[7];
  const float* dec_b   = (const float*)d_in[8];
  const float* proj_W  = (const float*)d_in[9];

  char* w = (char*)d_ws;
  auto carve = [&](size_t bytes) -> char* {
    char* p = w; w += (bytes + 255) & ~(size_t)255; return p;
  };
  const size_t WSZ = 2048 * 512 * 2;  // [2048][512] bf16
  ushort_t* eWx_hi = (ushort_t*)carve(WSZ); ushort_t* eWx_lo = (ushort_t*)carve(WSZ);
  ushort_t* eWh_hi = (ushort_t*)carve(WSZ); ushort_t* eWh_lo = (ushort_t*)carve(WSZ);
  ushort_t* dWx_hi = (ushort_t*)carve(WSZ); ushort_t* dWx_lo = (ushort_t*)carve(WSZ);
  ushort_t* dWh_hi = (ushort_t*)carve(WSZ); ushort_t* dWh_lo = (ushort_t*)carve(WSZ);
  ushort_t* pW_hi  = (ushort_t*)carve((size_t)32000 * 512 * 2);
  ushort_t* pW_lo  = (ushort_t*)carve((size_t)32000 * 512 * 2);
  ushort_t* Ae_hi  = (ushort_t*)carve(WSZ); ushort_t* Ae_lo = (ushort_t*)carve(WSZ);
  ushort_t* Ad_hi  = (ushort_t*)carve(WSZ); ushort_t* Ad_lo = (ushort_t*)carve(WSZ);
  float* xz_enc = (float*)carve((size_t)64 * 32 * 2048 * 4);
  float* xz_dec = (float*)carve((size_t)64 * 32 * 2048 * 4);
  ushort_t* hs_hi = (ushort_t*)carve(WSZ); ushort_t* hs_lo = (ushort_t*)carve(WSZ);
  ushort_t* h_hi0 = (ushort_t*)carve(32 * 512 * 2);
  ushort_t* h_lo0 = (ushort_t*)carve(32 * 512 * 2);
  ushort_t* h_hi1 = (ushort_t*)carve(32 * 512 * 2);
  ushort_t* h_lo1 = (ushort_t*)carve(32 * 512 * 2);
  int* flags = (int*)carve(BAR_NB * 32 * sizeof(int));

  dim3 blk(256);
  // Weight transpose+split (B^T layout [n][k] for contiguous MFMA B-fragments)
  transpose_split<<<dim3(32, 8),  blk, 0, stream>>>(enc_W, 2048, 0,   eWx_hi, eWx_lo);
  transpose_split<<<dim3(32, 8),  blk, 0, stream>>>(enc_W, 2048, 512, eWh_hi, eWh_lo);
  transpose_split<<<dim3(32, 8),  blk, 0, stream>>>(dec_W, 2048, 0,   dWx_hi, dWx_lo);
  transpose_split<<<dim3(32, 8),  blk, 0, stream>>>(dec_W, 2048, 512, dWh_hi, dWh_lo);
  transpose_split<<<dim3(500, 8), blk, 0, stream>>>(proj_W, 32000, 0, pW_hi, pW_lo);

  // Embedding gather+split (rows m = t*32+b)
  embed_split<<<2048, 128, 0, stream>>>(enc_ids, E, Ae_hi, Ae_lo, 64);
  embed_split<<<2048, 128, 0, stream>>>(dec_ids, E, Ad_hi, Ad_lo, 64);

  // Input-side gate pre-activations: xz[t][b][4H] = X @ W_x + b
  gemm_split<<<dim3(16, 16), blk, 0, stream>>>(Ae_hi, Ae_lo, eWx_hi, eWx_lo,
                                               enc_b, xz_enc, 2048, 2048);
  gemm_split<<<dim3(16, 16), blk, 0, stream>>>(Ad_hi, Ad_lo, dWx_hi, dWx_lo,
                                               dec_b, xz_dec, 2048, 2048);

  // Recurrence (cooperative launch for co-residency; custom barrier inside)
  void* args[] = { &eWh_hi, &eWh_lo, &dWh_hi, &dWh_lo,
                   (void*)&xz_enc, (void*)&xz_dec,
                   (void*)&len_enc, (void*)&len_dec,
                   &h_hi0, &h_lo0, &h_hi1, &h_lo1, &hs_hi, &hs_lo, &flags };
  hipLaunchCooperativeKernel((void*)lstm_recurrence, dim3(64), dim3(256),
                             args, 0, stream);

  // Vocab projection: out[b][t][v], row m = b*64+t matches hs layout.
  const float* nobias = nullptr;
  gemm_split<<<dim3(250, 16), blk, 0, stream>>>(hs_hi, hs_lo, pW_hi, pW_lo,
                                                nobias, (float*)d_out, 2048, 32000);
}